// Round 12
// baseline (2146.766 us; speedup 1.0000x reference)
//
#include <hip/hip_runtime.h>
#include <hip/hip_fp16.h>
#include <stdint.h>

#define GLOBAL_AS __attribute__((address_space(1)))
#define LDS_AS    __attribute__((address_space(3)))

typedef __attribute__((ext_vector_type(8))) short  short8;   // 8 bf16 = 4 VGPRs
typedef __attribute__((ext_vector_type(4))) float  floatx4;

static constexpr int B_   = 4096;
static constexpr int T_   = 28;
static constexpr int IN_  = 28;
static constexpr int H_   = 1024;
static constexpr int G4_  = 4096;   // 4*H
static constexpr int OUT_ = 10;
static constexpr int NT_  = 16;     // K-tiles of 64 over H=1024

// ---------- small helpers ----------
__device__ __forceinline__ float bf2f(unsigned short u) {
  union { uint32_t i; float f; } v; v.i = ((uint32_t)u) << 16; return v.f;
}
__device__ __forceinline__ unsigned short f2bf(float f) {  // RTNE
  union { float f; uint32_t i; } v; v.f = f;
  uint32_t x = v.i;
  uint32_t lsb = (x >> 16) & 1u;
  x += 0x7fffu + lsb;
  return (unsigned short)(x >> 16);
}
__device__ __forceinline__ float sigm(float x) {
  return __builtin_amdgcn_rcpf(1.f + __builtin_amdgcn_exp2f(-1.4426950408889634f * x));
}
__device__ __forceinline__ float tanh_f(float x) {
  return 1.f - 2.f * __builtin_amdgcn_rcpf(1.f + __builtin_amdgcn_exp2f(2.8853900817779268f * x));
}
__device__ __forceinline__ void stage16(const unsigned short* g, unsigned short* l) {
  __builtin_amdgcn_global_load_lds(
      (const GLOBAL_AS uint32_t*)g, (LDS_AS uint32_t*)l, 16, 0, 0);
}

// ---------- prologue: x -> bf16 [T][B][32] (k padded 28->32 with zeros) ----------
__global__ __launch_bounds__(256) void conv_x_kernel(const float* __restrict__ x,
                                                     unsigned short* __restrict__ xb) {
  int row = blockIdx.x * 256 + threadIdx.x;   // row = t*4096 + b
  int t  = row >> 12;
  int bb = row & 4095;
  const float* src = x + (bb * T_ + t) * IN_;
  unsigned short* dst = xb + row * 32;
#pragma unroll
  for (int k = 0; k < IN_; ++k) dst[k] = f2bf(src[k]);
  dst[28] = 0; dst[29] = 0; dst[30] = 0; dst[31] = 0;
}

// ---------- prologue: W_hh [1024][4096] fp32 -> Wp [4096][1024] bf16, transposed+interleaved ----------
// permuted n = g64*64 + gate*16 + hw  <->  orig col = gate*1024 + g64*16 + hw
__global__ __launch_bounds__(256) void perm_whh_kernel(const float* __restrict__ whh,
                                                       unsigned short* __restrict__ wp) {
  __shared__ float lds[64][17];
  int g64  = blockIdx.x >> 2;
  int gate = blockIdx.x & 3;
  int oc0  = gate * H_ + g64 * 16;
  int n0   = g64 * 64 + gate * 16;
  int tid  = threadIdx.x;
  for (int kc = 0; kc < 16; ++kc) {
    int k0 = kc * 64;
    __syncthreads();
#pragma unroll
    for (int e = 0; e < 4; ++e) {
      int idx = e * 256 + tid;
      int k = idx >> 4, cc = idx & 15;
      lds[k][cc] = whh[(k0 + k) * G4_ + oc0 + cc];
    }
    __syncthreads();
#pragma unroll
    for (int e = 0; e < 4; ++e) {
      int idx = e * 256 + tid;
      int n = idx >> 6, kk = idx & 63;
      wp[(n0 + n) * H_ + k0 + kk] = f2bf(lds[kk][n]);
    }
  }
}

// ---------- prologue: W_ih [28][4096] -> Wip [4096][32] bf16 transposed+interleaved ----------
__global__ __launch_bounds__(256) void perm_wih_kernel(const float* __restrict__ wih,
                                                       unsigned short* __restrict__ wip) {
  __shared__ float lds[28][17];
  int g64  = blockIdx.x >> 2;
  int gate = blockIdx.x & 3;
  int oc0  = gate * H_ + g64 * 16;
  int n0   = g64 * 64 + gate * 16;
  int tid  = threadIdx.x;
  for (int idx = tid; idx < 448; idx += 256) {
    int k = idx >> 4, cc = idx & 15;
    lds[k][cc] = wih[k * G4_ + oc0 + cc];
  }
  __syncthreads();
#pragma unroll
  for (int e = 0; e < 2; ++e) {
    int idx = e * 256 + tid;
    int n = idx >> 5, kk = idx & 31;
    wip[(n0 + n) * 32 + kk] = (kk < IN_) ? f2bf(lds[kk][n]) : (unsigned short)0;
  }
}

// ====== LSTM step: 256x128 tile, A DIRECT global->VGPR, B double-buffered LDS (32 KB) ======
// 8 waves (4M x 2N), wave-tile 64x64, BK=64, 2 blocks/CU (round-9 geometry).
// LDS-port relief: A fragments load straight from global (h k-slice L1-resident for the
// wn-pair re-read); only B staged (16 KB/tile, 2 bufs). Stage 2 tiles ahead:
//   {compute kt} BAR {stage B(kt+2) -> buf of B(kt)} vmcnt(2) BAR
// vmcnt(2) targets DMA issued one full compute-phase earlier (free); in-order vmem
// retirement makes B(kt) provably landed before compute-kt (A waits retire older B).
__global__ __launch_bounds__(512, 4) void lstm_step_kernel(
    const unsigned short* __restrict__ hprev,   // [B][H] bf16
    const unsigned short* __restrict__ wp,      // [4096][1024] bf16 (permuted^T)
    const unsigned short* __restrict__ xbt,     // [B][32] bf16 (this t)
    const unsigned short* __restrict__ wip,     // [4096][32] bf16 (permuted^T)
    const float* __restrict__ bias,             // [4096] original gate order
    unsigned short* __restrict__ cst,           // [B][H] fp16 cell state
    unsigned short* __restrict__ hnext,         // [B][H] bf16
    int first) {
  __shared__ __align__(16) unsigned short lds[16384];   // 32 KB: B buf0 [0,8192)u, buf1 [8192,16384)u

  const int tid = threadIdx.x;           // 0..511
  const int w   = tid >> 6;              // wave 0..7
  const int l   = tid & 63;
  const int wm  = w >> 1;                // 0..3  (M quarter, 64 rows)
  const int wn  = w & 1;                 // 0..1  (N half, 64 cols)
  const int lc  = l & 15;
  const int lk  = l >> 4;                // 0..3

  // XCD-aware swizzle: 8x8 (bx,by) rectangle per XCD (bijective, 512 = 8 XCD * 64)
  const int hid = blockIdx.x;
  const int xcd = hid & 7, q = hid >> 3;           // q 0..63
  const int bx  = (xcd & 1) * 8 + (q & 7);         // 0..15
  const int by  = (xcd >> 1) * 8 + (q >> 3);       // 0..31
  const int m0  = bx * 256;              // batch rows
  const int n0  = by * 128;              // permuted gate cols

  const int swz  = (lc & 7) << 4;        // B ds_read byte swizzle (128-B rows)
  const int swzx = (lc & 3) << 4;        // XB (64-B rows)

  // ---- B staging per-thread constants ----
  const int r8  = tid >> 3;              // chunk row 0..63
  const int c8s = ((tid & 7) * 8) ^ ((r8 & 7) * 8);    // pre-swizzled ushort col
  const int rx  = tid >> 2;              // XB row 0..127
  const int cxs = ((tid & 3) * 8) ^ ((rx & 3) * 8);    // pre-swizzled (64-B rows)

  auto stageB = [&](int bufU, int kt, int j) {   // B chunk j: cols j*64..
    stage16(wp + (size_t)(n0 + j * 64 + r8) * H_ + kt * 64 + c8s,
            lds + bufU + j * 4096 + tid * 8);
  };
  auto stageXB = [&]() {                 // XB [128][32] at ushort 0 (buf0 overlay)
    stage16(wip + (size_t)(n0 + rx) * 32 + cxs, lds + tid * 8);
  };
  auto ldsr = [&](int byteoff) -> short8 {
    return *reinterpret_cast<const short8*>(reinterpret_cast<const char*>(lds) + byteoff);
  };

  // ---- A direct-load bases (per-lane, 16B-aligned) ----
  const unsigned short* aRow = hprev + (size_t)(m0 + wm * 64 + lc) * H_ + lk * 8;
  const unsigned short* xRow = xbt + (size_t)(m0 + wm * 64 + lc) * 32 + lk * 8;

  floatx4 acc[4][4];                     // 64 regs (AGPR)
#pragma unroll
  for (int i = 0; i < 4; ++i)
#pragma unroll
    for (int j = 0; j < 4; ++j) acc[i][j] = (floatx4){0.f, 0.f, 0.f, 0.f};

  short8 a[4][2];                        // 32 VGPR
  short8 b[2][2];                        // 16 VGPR (two B passes)

#define LOAD_A_DIR(KT)                                                               \
  _Pragma("unroll") for (int m_ = 0; m_ < 4; ++m_)                                   \
  _Pragma("unroll") for (int k_ = 0; k_ < 2; ++k_)                                   \
    a[m_][k_] = *reinterpret_cast<const short8*>(aRow + m_ * (16 * H_) + (KT) * 64 + k_ * 32);

#define LOAD_B(BUFBYTE, P)                                                           \
  _Pragma("unroll") for (int n_ = 0; n_ < 2; ++n_)                                   \
  _Pragma("unroll") for (int k_ = 0; k_ < 2; ++k_)                                   \
    b[n_][k_] = ldsr((BUFBYTE) + (wn * 64 + ((P) * 2 + n_) * 16 + lc) * 128 +        \
                     ((k_ * 64 + lk * 16) ^ swz));

#define MFMA_P(P)                                                                    \
  __builtin_amdgcn_s_setprio(1);                                                     \
  _Pragma("unroll") for (int m_ = 0; m_ < 4; ++m_)                                   \
  _Pragma("unroll") for (int n_ = 0; n_ < 2; ++n_)                                   \
  _Pragma("unroll") for (int k_ = 0; k_ < 2; ++k_)                                   \
    acc[m_][(P) * 2 + n_] = __builtin_amdgcn_mfma_f32_16x16x32_bf16(                 \
        a[m_][k_], b[n_][k_], acc[m_][(P) * 2 + n_], 0, 0, 0);                       \
  __builtin_amdgcn_s_setprio(0);

#define BAR_ONLY                                                                     \
  __builtin_amdgcn_sched_barrier(0);                                                 \
  __builtin_amdgcn_s_barrier();                                                      \
  __builtin_amdgcn_sched_barrier(0);

#define BAR_VM(VM)                                                                   \
  __builtin_amdgcn_sched_barrier(0);                                                 \
  asm volatile("s_waitcnt vmcnt(" #VM ")" ::: "memory");                             \
  __builtin_amdgcn_s_barrier();                                                      \
  __builtin_amdgcn_sched_barrier(0);

  if (first) {
    // x-projection only: XB staged, XA direct
    stageXB();
    BAR_VM(0)
    short8 xb4[4];
#pragma unroll
    for (int nf = 0; nf < 4; ++nf)
      xb4[nf] = ldsr((wn * 64 + nf * 16 + lc) * 64 + ((lk * 16) ^ swzx));
    __builtin_amdgcn_s_setprio(1);
#pragma unroll
    for (int mf = 0; mf < 4; ++mf) {
      short8 xa = *reinterpret_cast<const short8*>(xRow + mf * (16 * 32));
#pragma unroll
      for (int nf = 0; nf < 4; ++nf)
        acc[mf][nf] = __builtin_amdgcn_mfma_f32_16x16x32_bf16(xa, xb4[nf], acc[mf][nf], 0, 0, 0);
    }
    __builtin_amdgcn_s_setprio(0);
  } else {
    // ---- prologue: XB -> buf0 overlay; B(t0) -> buf1 ----
    stageXB();
    stageB(8192, 0, 0); stageB(8192, 0, 1);
    BAR_VM(2)                                   // XB landed (t0's 2 in flight)
    // ---- x compute: XB from LDS, XA direct ----
    {
      short8 xb4[4];
#pragma unroll
      for (int nf = 0; nf < 4; ++nf)
        xb4[nf] = ldsr((wn * 64 + nf * 16 + lc) * 64 + ((lk * 16) ^ swzx));
      __builtin_amdgcn_s_setprio(1);
#pragma unroll
      for (int mf = 0; mf < 4; ++mf) {
        short8 xa = *reinterpret_cast<const short8*>(xRow + mf * (16 * 32));
#pragma unroll
        for (int nf = 0; nf < 4; ++nf)
          acc[mf][nf] = __builtin_amdgcn_mfma_f32_16x16x32_bf16(xa, xb4[nf], acc[mf][nf], 0, 0, 0);
      }
      __builtin_amdgcn_s_setprio(0);
    }
    BAR_ONLY                                    // XB reads retired; buf0 free
    // ---- B(t1) -> buf0 (overwrites XB) ----
    stageB(0, 1, 0); stageB(0, 1, 1);
    BAR_VM(2)                                   // B(t0) landed (B(t1) may fly; XA waits already retired B(t0))
    // ---- main loop: tile kt reads buf((kt&1)^1); stage kt+2 into same buf after compute ----
    for (int kt = 0; kt < NT_; ++kt) {
      const int bufB = ((kt & 1) ^ 1) * 16384;  // byte base of this tile's B
      LOAD_A_DIR(kt)
      LOAD_B(bufB, 0)
      MFMA_P(0)
      LOAD_B(bufB, 1)
      MFMA_P(1)
      if (kt + 1 < NT_) {
        BAR_ONLY                                // all waves' B(kt) reads retired (WAR)
        if (kt + 2 < NT_) {
          stageB(bufB / 2, kt + 2, 0); stageB(bufB / 2, kt + 2, 1);  // ushort base = byte/2
          BAR_VM(2)                             // B(kt+1) landed (B(kt+2) in flight) -- free
        } else {
          BAR_VM(0)                             // tail: B(15) landed (issued 2 phases ago) -- free
        }
      }
    }
  }

  // ---- epilogue: frag nf == gate; fused LSTM cell update; c in fp16 ----
  const int jj  = (by * 2 + wn) * 16 + lc;     // h column 0..1023
  const float bi  = bias[jj];
  const float bf_ = bias[H_ + jj];
  const float bg_ = bias[2 * H_ + jj];
  const float bo_ = bias[3 * H_ + jj];
#pragma unroll
  for (int mf = 0; mf < 4; ++mf) {
    const int rbase = m0 + wm * 64 + mf * 16 + lk * 4;
#pragma unroll
    for (int r = 0; r < 4; ++r) {
      const size_t idx = (size_t)(rbase + r) * H_ + jj;
      float ig = sigm(acc[mf][0][r] + bi);
      float fg = sigm(acc[mf][1][r] + bf_);
      float gg = tanh_f(acc[mf][2][r] + bg_);
      float og = sigm(acc[mf][3][r] + bo_);
      float cp = first ? 0.f : __half2float(__ushort_as_half(cst[idx]));
      float cn = fg * cp + ig * gg;
      cst[idx] = __half_as_ushort(__float2half(cn));
      hnext[idx] = f2bf(og * tanh_f(cn));
    }
  }
#undef LOAD_A_DIR
#undef LOAD_B
#undef MFMA_P
#undef BAR_ONLY
#undef BAR_VM
}

// ---------- classifier: out = h @ Wc + bc ----------
__global__ __launch_bounds__(256) void cls_kernel(const unsigned short* __restrict__ h,
                                                  const float* __restrict__ wc,
                                                  const float* __restrict__ bc,
                                                  float* __restrict__ out) {
  int w = threadIdx.x >> 6, l = threadIdx.x & 63;
  int row = blockIdx.x * 4 + w;
  float acc[OUT_];
#pragma unroll
  for (int o = 0; o < OUT_; ++o) acc[o] = 0.f;
  const unsigned short* hr = h + row * H_;
  for (int k = l; k < H_; k += 64) {
    float hv = bf2f(hr[k]);
#pragma unroll
    for (int o = 0; o < OUT_; ++o) acc[o] += hv * wc[k * OUT_ + o];
  }
#pragma unroll
  for (int o = 0; o < OUT_; ++o) {
    float v = acc[o];
#pragma unroll
    for (int s = 32; s > 0; s >>= 1) v += __shfl_down(v, s, 64);
    if (l == 0) out[row * OUT_ + o] = v + bc[o];
  }
}

extern "C" void kernel_launch(void* const* d_in, const int* in_sizes, int n_in,
                              void* d_out, int out_size, void* d_ws, size_t ws_size,
                              hipStream_t stream) {
  const float* x    = (const float*)d_in[0];
  const float* wih  = (const float*)d_in[1];
  const float* whh  = (const float*)d_in[2];
  const float* bias = (const float*)d_in[3];
  const float* wc   = (const float*)d_in[4];
  const float* bc   = (const float*)d_in[5];
  float* out = (float*)d_out;

  char* ws = (char*)d_ws;
  unsigned short* wp  = (unsigned short*)(ws);                 //  8 MB  permuted W_hh^T bf16
  unsigned short* wip = (unsigned short*)(ws + 8388608);       //  256KB permuted W_ih^T bf16
  unsigned short* xb  = (unsigned short*)(ws + 8650752);       //  7 MB  x bf16 [T][B][32]
  unsigned short* h0  = (unsigned short*)(ws + 15990784);      //  8 MB
  unsigned short* h1  = (unsigned short*)(ws + 24379392);      //  8 MB
  unsigned short* cst = (unsigned short*)(ws + 32768000);      //  8 MB  fp16 cell state

  hipLaunchKernelGGL(conv_x_kernel,  dim3(448), dim3(256), 0, stream, x, xb);
  hipLaunchKernelGGL(perm_whh_kernel, dim3(256), dim3(256), 0, stream, whh, wp);
  hipLaunchKernelGGL(perm_wih_kernel, dim3(256), dim3(256), 0, stream, wih, wip);

  unsigned short* hb[2] = {h0, h1};
  for (int t = 0; t < T_; ++t) {
    unsigned short* hn = hb[t & 1];
    unsigned short* hp = hb[(t & 1) ^ 1];
    hipLaunchKernelGGL(lstm_step_kernel, dim3(512), dim3(512), 0, stream,
                       hp, wp, xb + (size_t)t * (B_ * 32), wip, bias, cst, hn,
                       (t == 0) ? 1 : 0);
  }
  hipLaunchKernelGGL(cls_kernel, dim3(1024), dim3(256), 0, stream, hb[1], wc, bc, out);
}

// Round 13
// 1181.010 us; speedup vs baseline: 1.8177x; 1.8177x over previous
//
#include <hip/hip_runtime.h>
#include <hip/hip_fp16.h>
#include <stdint.h>

#define GLOBAL_AS __attribute__((address_space(1)))
#define LDS_AS    __attribute__((address_space(3)))

typedef __attribute__((ext_vector_type(8))) short  short8;   // 8 bf16 = 4 VGPRs
typedef __attribute__((ext_vector_type(4))) float  floatx4;

static constexpr int B_   = 4096;
static constexpr int T_   = 28;
static constexpr int IN_  = 28;
static constexpr int H_   = 1024;
static constexpr int G4_  = 4096;   // 4*H
static constexpr int OUT_ = 10;
static constexpr int NT_  = 16;     // K-tiles of 64 over H=1024

// ---------- small helpers ----------
__device__ __forceinline__ float bf2f(unsigned short u) {
  union { uint32_t i; float f; } v; v.i = ((uint32_t)u) << 16; return v.f;
}
__device__ __forceinline__ unsigned short f2bf(float f) {  // RTNE
  union { float f; uint32_t i; } v; v.f = f;
  uint32_t x = v.i;
  uint32_t lsb = (x >> 16) & 1u;
  x += 0x7fffu + lsb;
  return (unsigned short)(x >> 16);
}
__device__ __forceinline__ float sigm(float x) {
  return __builtin_amdgcn_rcpf(1.f + __builtin_amdgcn_exp2f(-1.4426950408889634f * x));
}
__device__ __forceinline__ float tanh_f(float x) {
  return 1.f - 2.f * __builtin_amdgcn_rcpf(1.f + __builtin_amdgcn_exp2f(2.8853900817779268f * x));
}
__device__ __forceinline__ void stage16(const unsigned short* g, unsigned short* l) {
  __builtin_amdgcn_global_load_lds(
      (const GLOBAL_AS uint32_t*)g, (LDS_AS uint32_t*)l, 16, 0, 0);
}

// ---------- prologue: x -> bf16 [T][B][32] (k padded 28->32 with zeros) ----------
__global__ __launch_bounds__(256) void conv_x_kernel(const float* __restrict__ x,
                                                     unsigned short* __restrict__ xb) {
  int row = blockIdx.x * 256 + threadIdx.x;   // row = t*4096 + b
  int t  = row >> 12;
  int bb = row & 4095;
  const float* src = x + (bb * T_ + t) * IN_;
  unsigned short* dst = xb + row * 32;
#pragma unroll
  for (int k = 0; k < IN_; ++k) dst[k] = f2bf(src[k]);
  dst[28] = 0; dst[29] = 0; dst[30] = 0; dst[31] = 0;
}

// ---------- prologue: W_hh [1024][4096] fp32 -> Wp [4096][1024] bf16, transposed+interleaved ----------
// permuted n = g64*64 + gate*16 + hw  <->  orig col = gate*1024 + g64*16 + hw
__global__ __launch_bounds__(256) void perm_whh_kernel(const float* __restrict__ whh,
                                                       unsigned short* __restrict__ wp) {
  __shared__ float lds[64][17];
  int g64  = blockIdx.x >> 2;
  int gate = blockIdx.x & 3;
  int oc0  = gate * H_ + g64 * 16;
  int n0   = g64 * 64 + gate * 16;
  int tid  = threadIdx.x;
  for (int kc = 0; kc < 16; ++kc) {
    int k0 = kc * 64;
    __syncthreads();
#pragma unroll
    for (int e = 0; e < 4; ++e) {
      int idx = e * 256 + tid;
      int k = idx >> 4, cc = idx & 15;
      lds[k][cc] = whh[(k0 + k) * G4_ + oc0 + cc];
    }
    __syncthreads();
#pragma unroll
    for (int e = 0; e < 4; ++e) {
      int idx = e * 256 + tid;
      int n = idx >> 6, kk = idx & 63;
      wp[(n0 + n) * H_ + k0 + kk] = f2bf(lds[kk][n]);
    }
  }
}

// ---------- prologue: W_ih [28][4096] -> Wip [4096][32] bf16 transposed+interleaved ----------
__global__ __launch_bounds__(256) void perm_wih_kernel(const float* __restrict__ wih,
                                                       unsigned short* __restrict__ wip) {
  __shared__ float lds[28][17];
  int g64  = blockIdx.x >> 2;
  int gate = blockIdx.x & 3;
  int oc0  = gate * H_ + g64 * 16;
  int n0   = g64 * 64 + gate * 16;
  int tid  = threadIdx.x;
  for (int idx = tid; idx < 448; idx += 256) {
    int k = idx >> 4, cc = idx & 15;
    lds[k][cc] = wih[k * G4_ + oc0 + cc];
  }
  __syncthreads();
#pragma unroll
  for (int e = 0; e < 2; ++e) {
    int idx = e * 256 + tid;
    int n = idx >> 5, kk = idx & 31;
    wip[(n0 + n) * 32 + kk] = (kk < IN_) ? f2bf(lds[kk][n]) : (unsigned short)0;
  }
}

// ====== LSTM step: 256x128 tile, 4 waves (2M x 2N, wave-tile 128x64), 2 blocks/CU ======
// Round-9 phase structure exactly: {LOAD frags + MFMA} BAR {stage next tile} vmcnt(0) BAR.
// Change vs round 9: squarer wave decomposition cuts LDS read duplication 25%
// (4 waves x 24 b128 = 96/block vs 8 waves x 16 = 128) -- LDS port is the measured wall.
// VGPR: acc 128 + a 64 + b 16 + addr ~ 225 < 256 cap at 2 waves/SIMD.
// T2 swizzle via pre-swizzled global source; x phase layout-matched; c-state fp16.
__global__ __launch_bounds__(256, 2) void lstm_step_kernel(
    const unsigned short* __restrict__ hprev,   // [B][H] bf16
    const unsigned short* __restrict__ wp,      // [4096][1024] bf16 (permuted^T)
    const unsigned short* __restrict__ xbt,     // [B][32] bf16 (this t)
    const unsigned short* __restrict__ wip,     // [4096][32] bf16 (permuted^T)
    const float* __restrict__ bias,             // [4096] original gate order
    unsigned short* __restrict__ cst,           // [B][H] fp16 cell state
    unsigned short* __restrict__ hnext,         // [B][H] bf16
    int first) {
  __shared__ __align__(16) unsigned short lds[24576];   // 48 KB: A[256][64] | B[128][64]

  const int tid = threadIdx.x;           // 0..255
  const int w   = tid >> 6;              // wave 0..3
  const int l   = tid & 63;
  const int wm  = w >> 1;                // 0..1  (M half, 128 rows)
  const int wn  = w & 1;                 // 0..1  (N half, 64 cols)
  const int lc  = l & 15;
  const int lk  = l >> 4;                // 0..3

  // XCD-aware swizzle: 8x8 (bx,by) rectangle per XCD (bijective, 512 = 8 XCD * 64)
  const int hid = blockIdx.x;
  const int xcd = hid & 7, q = hid >> 3;           // q 0..63
  const int bx  = (xcd & 1) * 8 + (q & 7);         // 0..15
  const int by  = (xcd >> 1) * 8 + (q >> 3);       // 0..31
  const int m0  = bx * 256;              // batch rows
  const int n0  = by * 128;              // permuted gate cols

  const int swz  = (lc & 7) << 4;        // main tiles (128-B rows)
  const int swzx = (lc & 3) << 4;        // x tiles (64-B rows)

  // ---- staging per-thread constants ----
  const int r8  = tid >> 3;              // main chunk row 0..31
  const int c8s = ((tid & 7) * 8) ^ ((r8 & 7) * 8);    // pre-swizzled ushort col (128-B rows)
  const int rx  = tid >> 2;              // x chunk row 0..63
  const int cxs = ((tid & 3) * 8) ^ ((rx & 3) * 8);    // pre-swizzled (64-B rows)

  auto stageA = [&](int kt, int j) {     // A chunk j (0..7): rows j*32.., 2048 u each
    stage16(hprev + (size_t)(m0 + j * 32 + r8) * H_ + kt * 64 + c8s,
            lds + j * 2048 + tid * 8);
  };
  auto stageB = [&](int kt, int j) {     // B chunk j (0..3): cols j*32.., region 16384..24576 u
    stage16(wp + (size_t)(n0 + j * 32 + r8) * H_ + kt * 64 + c8s,
            lds + 16384 + j * 2048 + tid * 8);
  };
  auto stageXA = [&](int i) {            // XA [256][32] at u 0, chunks i 0..3 (64 rows each)
    stage16(xbt + (size_t)(m0 + i * 64 + rx) * 32 + cxs, lds + i * 2048 + tid * 8);
  };
  auto stageXB = [&](int i) {            // XB [128][32] at u 8192, chunks i 0..1
    stage16(wip + (size_t)(n0 + i * 64 + rx) * 32 + cxs, lds + 8192 + i * 2048 + tid * 8);
  };
  auto ldsr = [&](int byteoff) -> short8 {
    return *reinterpret_cast<const short8*>(reinterpret_cast<const char*>(lds) + byteoff);
  };

  floatx4 acc[8][4];                     // 128 regs: [mf][nf], wave-tile 128x64
#pragma unroll
  for (int i = 0; i < 8; ++i)
#pragma unroll
    for (int j = 0; j < 4; ++j) acc[i][j] = (floatx4){0.f, 0.f, 0.f, 0.f};

  short8 a[8][2];                        // 64 VGPR
  short8 b[2][2];                        // 16 VGPR (two B passes)

#define LOAD_A                                                                       \
  _Pragma("unroll") for (int m_ = 0; m_ < 8; ++m_)                                   \
  _Pragma("unroll") for (int k_ = 0; k_ < 2; ++k_)                                   \
    a[m_][k_] = ldsr((wm * 128 + m_ * 16 + lc) * 128 + ((k_ * 64 + lk * 16) ^ swz));

#define LOAD_B(P)                                                                    \
  _Pragma("unroll") for (int n_ = 0; n_ < 2; ++n_)                                   \
  _Pragma("unroll") for (int k_ = 0; k_ < 2; ++k_)                                   \
    b[n_][k_] = ldsr(32768 + (wn * 64 + ((P) * 2 + n_) * 16 + lc) * 128 +            \
                     ((k_ * 64 + lk * 16) ^ swz));

#define MFMA_P(P)                                                                    \
  __builtin_amdgcn_s_setprio(1);                                                     \
  _Pragma("unroll") for (int m_ = 0; m_ < 8; ++m_)                                   \
  _Pragma("unroll") for (int n_ = 0; n_ < 2; ++n_)                                   \
  _Pragma("unroll") for (int k_ = 0; k_ < 2; ++k_)                                   \
    acc[m_][(P) * 2 + n_] = __builtin_amdgcn_mfma_f32_16x16x32_bf16(                 \
        a[m_][k_], b[n_][k_], acc[m_][(P) * 2 + n_], 0, 0, 0);                       \
  __builtin_amdgcn_s_setprio(0);

#define BAR_ONLY                                                                     \
  __builtin_amdgcn_sched_barrier(0);                                                 \
  __builtin_amdgcn_s_barrier();                                                      \
  __builtin_amdgcn_sched_barrier(0);

#define BAR_VM0                                                                      \
  __builtin_amdgcn_sched_barrier(0);                                                 \
  asm volatile("s_waitcnt vmcnt(0)" ::: "memory");                                   \
  __builtin_amdgcn_s_barrier();                                                      \
  __builtin_amdgcn_sched_barrier(0);

  // ---- x phase: stage, drain, MFMA (K=32) ----
  stageXA(0); stageXA(1); stageXA(2); stageXA(3);
  stageXB(0); stageXB(1);
  BAR_VM0
  {
    short8 xb4[4];
#pragma unroll
    for (int nf = 0; nf < 4; ++nf)
      xb4[nf] = ldsr(16384 + (wn * 64 + nf * 16 + lc) * 64 + ((lk * 16) ^ swzx));
    __builtin_amdgcn_s_setprio(1);
#pragma unroll
    for (int mf = 0; mf < 8; ++mf) {
      short8 xa = ldsr((wm * 128 + mf * 16 + lc) * 64 + ((lk * 16) ^ swzx));
#pragma unroll
      for (int nf = 0; nf < 4; ++nf)
        acc[mf][nf] = __builtin_amdgcn_mfma_f32_16x16x32_bf16(xa, xb4[nf], acc[mf][nf], 0, 0, 0);
    }
    __builtin_amdgcn_s_setprio(0);
  }

  if (!first) {
    BAR_ONLY                                   // x reads consumed (counted lgkm pinned pre-BAR)
    // ---- tile 0 stage ----
#pragma unroll
    for (int j = 0; j < 8; ++j) stageA(0, j);
#pragma unroll
    for (int j = 0; j < 4; ++j) stageB(0, j);
    BAR_VM0
    // ---- main loop: single-buffer, phase-separated stage (round-9 structure) ----
    for (int kt = 0; kt < NT_; ++kt) {
      LOAD_A
      LOAD_B(0)
      MFMA_P(0)
      LOAD_B(1)
      MFMA_P(1)
      if (kt + 1 < NT_) {
        BAR_ONLY                               // all waves' tile-kt reads retired
#pragma unroll
        for (int j = 0; j < 8; ++j) stageA(kt + 1, j);
#pragma unroll
        for (int j = 0; j < 4; ++j) stageB(kt + 1, j);
        BAR_VM0                                // tile kt+1 landed
      }
    }
  }

  // ---- epilogue: frag nf == gate; fused LSTM cell update; c in fp16 ----
  const int jj  = (by * 2 + wn) * 16 + lc;     // h column 0..1023
  const float bi  = bias[jj];
  const float bf_ = bias[H_ + jj];
  const float bg_ = bias[2 * H_ + jj];
  const float bo_ = bias[3 * H_ + jj];
#pragma unroll
  for (int mf = 0; mf < 8; ++mf) {
    const int rbase = m0 + wm * 128 + mf * 16 + lk * 4;
#pragma unroll
    for (int r = 0; r < 4; ++r) {
      const size_t idx = (size_t)(rbase + r) * H_ + jj;
      float ig = sigm(acc[mf][0][r] + bi);
      float fg = sigm(acc[mf][1][r] + bf_);
      float gg = tanh_f(acc[mf][2][r] + bg_);
      float og = sigm(acc[mf][3][r] + bo_);
      float cp = first ? 0.f : __half2float(__ushort_as_half(cst[idx]));
      float cn = fg * cp + ig * gg;
      cst[idx] = __half_as_ushort(__float2half(cn));
      hnext[idx] = f2bf(og * tanh_f(cn));
    }
  }
#undef LOAD_A
#undef LOAD_B
#undef MFMA_P
#undef BAR_ONLY
#undef BAR_VM0
}

// ---------- classifier: out = h @ Wc + bc ----------
__global__ __launch_bounds__(256) void cls_kernel(const unsigned short* __restrict__ h,
                                                  const float* __restrict__ wc,
                                                  const float* __restrict__ bc,
                                                  float* __restrict__ out) {
  int w = threadIdx.x >> 6, l = threadIdx.x & 63;
  int row = blockIdx.x * 4 + w;
  float acc[OUT_];
#pragma unroll
  for (int o = 0; o < OUT_; ++o) acc[o] = 0.f;
  const unsigned short* hr = h + row * H_;
  for (int k = l; k < H_; k += 64) {
    float hv = bf2f(hr[k]);
#pragma unroll
    for (int o = 0; o < OUT_; ++o) acc[o] += hv * wc[k * OUT_ + o];
  }
#pragma unroll
  for (int o = 0; o < OUT_; ++o) {
    float v = acc[o];
#pragma unroll
    for (int s = 32; s > 0; s >>= 1) v += __shfl_down(v, s, 64);
    if (l == 0) out[row * OUT_ + o] = v + bc[o];
  }
}

extern "C" void kernel_launch(void* const* d_in, const int* in_sizes, int n_in,
                              void* d_out, int out_size, void* d_ws, size_t ws_size,
                              hipStream_t stream) {
  const float* x    = (const float*)d_in[0];
  const float* wih  = (const float*)d_in[1];
  const float* whh  = (const float*)d_in[2];
  const float* bias = (const float*)d_in[3];
  const float* wc   = (const float*)d_in[4];
  const float* bc   = (const float*)d_in[5];
  float* out = (float*)d_out;

  char* ws = (char*)d_ws;
  unsigned short* wp  = (unsigned short*)(ws);                 //  8 MB  permuted W_hh^T bf16
  unsigned short* wip = (unsigned short*)(ws + 8388608);       //  256KB permuted W_ih^T bf16
  unsigned short* xb  = (unsigned short*)(ws + 8650752);       //  7 MB  x bf16 [T][B][32]
  unsigned short* h0  = (unsigned short*)(ws + 15990784);      //  8 MB
  unsigned short* h1  = (unsigned short*)(ws + 24379392);      //  8 MB
  unsigned short* cst = (unsigned short*)(ws + 32768000);      //  8 MB  fp16 cell state

  hipLaunchKernelGGL(conv_x_kernel,  dim3(448), dim3(256), 0, stream, x, xb);
  hipLaunchKernelGGL(perm_whh_kernel, dim3(256), dim3(256), 0, stream, whh, wp);
  hipLaunchKernelGGL(perm_wih_kernel, dim3(256), dim3(256), 0, stream, wih, wip);

  unsigned short* hb[2] = {h0, h1};
  for (int t = 0; t < T_; ++t) {
    unsigned short* hn = hb[t & 1];
    unsigned short* hp = hb[(t & 1) ^ 1];
    hipLaunchKernelGGL(lstm_step_kernel, dim3(512), dim3(256), 0, stream,
                       hp, wp, xb + (size_t)t * (B_ * 32), wip, bias, cst, hn,
                       (t == 0) ? 1 : 0);
  }
  hipLaunchKernelGGL(cls_kernel, dim3(1024), dim3(256), 0, stream, hb[1], wc, bc, out);
}

// Round 14
// 1155.345 us; speedup vs baseline: 1.8581x; 1.0222x over previous
//
#include <hip/hip_runtime.h>
#include <hip/hip_fp16.h>
#include <stdint.h>

#define GLOBAL_AS __attribute__((address_space(1)))
#define LDS_AS    __attribute__((address_space(3)))

typedef __attribute__((ext_vector_type(8))) short  short8;   // 8 bf16 = 4 VGPRs
typedef __attribute__((ext_vector_type(4))) float  floatx4;

static constexpr int B_   = 4096;
static constexpr int T_   = 28;
static constexpr int IN_  = 28;
static constexpr int H_   = 1024;
static constexpr int G4_  = 4096;   // 4*H
static constexpr int OUT_ = 10;
static constexpr int NT_  = 16;     // K-tiles of 64 over H=1024

// ---------- small helpers ----------
__device__ __forceinline__ float bf2f(unsigned short u) {
  union { uint32_t i; float f; } v; v.i = ((uint32_t)u) << 16; return v.f;
}
__device__ __forceinline__ unsigned short f2bf(float f) {  // RTNE
  union { float f; uint32_t i; } v; v.f = f;
  uint32_t x = v.i;
  uint32_t lsb = (x >> 16) & 1u;
  x += 0x7fffu + lsb;
  return (unsigned short)(x >> 16);
}
__device__ __forceinline__ float sigm(float x) {
  return __builtin_amdgcn_rcpf(1.f + __builtin_amdgcn_exp2f(-1.4426950408889634f * x));
}
__device__ __forceinline__ float tanh_f(float x) {
  return 1.f - 2.f * __builtin_amdgcn_rcpf(1.f + __builtin_amdgcn_exp2f(2.8853900817779268f * x));
}
__device__ __forceinline__ void stage16(const unsigned short* g, unsigned short* l) {
  __builtin_amdgcn_global_load_lds(
      (const GLOBAL_AS uint32_t*)g, (LDS_AS uint32_t*)l, 16, 0, 0);
}

// ---------- prologue: x -> bf16 [T][B][32] (k padded 28->32 with zeros) ----------
__global__ __launch_bounds__(256) void conv_x_kernel(const float* __restrict__ x,
                                                     unsigned short* __restrict__ xb) {
  int row = blockIdx.x * 256 + threadIdx.x;   // row = t*4096 + b
  int t  = row >> 12;
  int bb = row & 4095;
  const float* src = x + (bb * T_ + t) * IN_;
  unsigned short* dst = xb + row * 32;
#pragma unroll
  for (int k = 0; k < IN_; ++k) dst[k] = f2bf(src[k]);
  dst[28] = 0; dst[29] = 0; dst[30] = 0; dst[31] = 0;
}

// ---------- prologue: W_hh [1024][4096] fp32 -> Wp [4096][1024] bf16, transposed+interleaved ----------
// permuted n = g64*64 + gate*16 + hw  <->  orig col = gate*1024 + g64*16 + hw
__global__ __launch_bounds__(256) void perm_whh_kernel(const float* __restrict__ whh,
                                                       unsigned short* __restrict__ wp) {
  __shared__ float lds[64][17];
  int g64  = blockIdx.x >> 2;
  int gate = blockIdx.x & 3;
  int oc0  = gate * H_ + g64 * 16;
  int n0   = g64 * 64 + gate * 16;
  int tid  = threadIdx.x;
  for (int kc = 0; kc < 16; ++kc) {
    int k0 = kc * 64;
    __syncthreads();
#pragma unroll
    for (int e = 0; e < 4; ++e) {
      int idx = e * 256 + tid;
      int k = idx >> 4, cc = idx & 15;
      lds[k][cc] = whh[(k0 + k) * G4_ + oc0 + cc];
    }
    __syncthreads();
#pragma unroll
    for (int e = 0; e < 4; ++e) {
      int idx = e * 256 + tid;
      int n = idx >> 6, kk = idx & 63;
      wp[(n0 + n) * H_ + k0 + kk] = f2bf(lds[kk][n]);
    }
  }
}

// ---------- prologue: W_ih [28][4096] -> Wip [4096][32] bf16 transposed+interleaved ----------
__global__ __launch_bounds__(256) void perm_wih_kernel(const float* __restrict__ wih,
                                                       unsigned short* __restrict__ wip) {
  __shared__ float lds[28][17];
  int g64  = blockIdx.x >> 2;
  int gate = blockIdx.x & 3;
  int oc0  = gate * H_ + g64 * 16;
  int n0   = g64 * 64 + gate * 16;
  int tid  = threadIdx.x;
  for (int idx = tid; idx < 448; idx += 256) {
    int k = idx >> 4, cc = idx & 15;
    lds[k][cc] = wih[k * G4_ + oc0 + cc];
  }
  __syncthreads();
#pragma unroll
  for (int e = 0; e < 2; ++e) {
    int idx = e * 256 + tid;
    int n = idx >> 5, kk = idx & 31;
    wip[(n0 + n) * 32 + kk] = (kk < IN_) ? f2bf(lds[kk][n]) : (unsigned short)0;
  }
}

// ====== LSTM step: 256x128 tile, A DOUBLE-buffered (80 KB LDS), 2 blocks/CU ======
// 8 waves (4M x 2N), wave-tile 64x64, BK=64 -- round-9 geometry (best: 41 us).
// LDS: Abuf0 [0,16384)u | Abuf1 [16384,32768)u | Bbuf [32768,40960)u = 80 KB = 160/2.
// Per tile: stageA(kt+1)->other A-buf issued at phase TOP (WAR-safe: that buf's reads
// retired before the PREVIOUS phase's end barrier) -- 32 KB of DMA overlaps compute.
// Then {compute} BAR {stageB(kt+1), 16 KB} vmcnt(0) BAR -- drain covers only B latency;
// A's chunks were issued ~2000 cyc earlier so their vmcnt is free.
__global__ __launch_bounds__(512, 4) void lstm_step_kernel(
    const unsigned short* __restrict__ hprev,   // [B][H] bf16
    const unsigned short* __restrict__ wp,      // [4096][1024] bf16 (permuted^T)
    const unsigned short* __restrict__ xbt,     // [B][32] bf16 (this t)
    const unsigned short* __restrict__ wip,     // [4096][32] bf16 (permuted^T)
    const float* __restrict__ bias,             // [4096] original gate order
    unsigned short* __restrict__ cst,           // [B][H] fp16 cell state
    unsigned short* __restrict__ hnext,         // [B][H] bf16
    int first) {
  __shared__ __align__(16) unsigned short lds[40960];   // 80 KB

  const int tid = threadIdx.x;           // 0..511
  const int w   = tid >> 6;              // wave 0..7
  const int l   = tid & 63;
  const int wm  = w >> 1;                // 0..3  (M quarter, 64 rows)
  const int wn  = w & 1;                 // 0..1  (N half, 64 cols)
  const int lc  = l & 15;
  const int lk  = l >> 4;                // 0..3

  // XCD-aware swizzle: 8x8 (bx,by) rectangle per XCD (bijective, 512 = 8 XCD * 64)
  const int hid = blockIdx.x;
  const int xcd = hid & 7, q = hid >> 3;           // q 0..63
  const int bx  = (xcd & 1) * 8 + (q & 7);         // 0..15
  const int by  = (xcd >> 1) * 8 + (q >> 3);       // 0..31
  const int m0  = bx * 256;              // batch rows
  const int n0  = by * 128;              // permuted gate cols

  const int swz  = (lc & 7) << 4;        // main tiles (128-B rows)
  const int swzx = (lc & 3) << 4;        // x tiles (64-B rows)

  // ---- staging per-thread constants ----
  const int r8  = tid >> 3;              // main chunk row 0..63
  const int c8s = ((tid & 7) * 8) ^ ((r8 & 7) * 8);    // pre-swizzled ushort col
  const int rx  = tid >> 2;              // x chunk row 0..127
  const int cxs = ((tid & 3) * 8) ^ ((rx & 3) * 8);    // pre-swizzled (64-B rows)

  auto stageA = [&](int bufU, int kt, int j) {   // A chunk j (0..3): rows j*64.., 4096 u each
    stage16(hprev + (size_t)(m0 + j * 64 + r8) * H_ + kt * 64 + c8s,
            lds + bufU + j * 4096 + tid * 8);
  };
  auto stageB = [&](int kt, int j) {             // B chunk j (0..1): cols j*64..
    stage16(wp + (size_t)(n0 + j * 64 + r8) * H_ + kt * 64 + c8s,
            lds + 32768 + j * 4096 + tid * 8);
  };
  auto stageXA = [&](int half) {                 // XA [256][32] at u 0 (Abuf0 overlay)
    stage16(xbt + (size_t)(m0 + half * 128 + rx) * 32 + cxs,
            lds + half * 4096 + tid * 8);
  };
  auto stageXB = [&]() {                         // XB [128][32] at u 8192 (Abuf0 overlay)
    stage16(wip + (size_t)(n0 + rx) * 32 + cxs, lds + 8192 + tid * 8);
  };
  auto ldsr = [&](int byteoff) -> short8 {
    return *reinterpret_cast<const short8*>(reinterpret_cast<const char*>(lds) + byteoff);
  };

  floatx4 acc[4][4];                     // 64 regs (AGPR): [mf][nf], wave-tile 64x64
#pragma unroll
  for (int i = 0; i < 4; ++i)
#pragma unroll
    for (int j = 0; j < 4; ++j) acc[i][j] = (floatx4){0.f, 0.f, 0.f, 0.f};

  short8 a[4][2];                        // 32 VGPR
  short8 b[2][2];                        // 16 VGPR (two B passes)

#define LOAD_A(PB)                                                                   \
  _Pragma("unroll") for (int m_ = 0; m_ < 4; ++m_)                                   \
  _Pragma("unroll") for (int k_ = 0; k_ < 2; ++k_)                                   \
    a[m_][k_] = ldsr((PB) + (wm * 64 + m_ * 16 + lc) * 128 + ((k_ * 64 + lk * 16) ^ swz));

#define LOAD_B(P)                                                                    \
  _Pragma("unroll") for (int n_ = 0; n_ < 2; ++n_)                                   \
  _Pragma("unroll") for (int k_ = 0; k_ < 2; ++k_)                                   \
    b[n_][k_] = ldsr(65536 + (wn * 64 + ((P) * 2 + n_) * 16 + lc) * 128 +            \
                     ((k_ * 64 + lk * 16) ^ swz));

#define MFMA_P(P)                                                                    \
  __builtin_amdgcn_s_setprio(1);                                                     \
  _Pragma("unroll") for (int m_ = 0; m_ < 4; ++m_)                                   \
  _Pragma("unroll") for (int n_ = 0; n_ < 2; ++n_)                                   \
  _Pragma("unroll") for (int k_ = 0; k_ < 2; ++k_)                                   \
    acc[m_][(P) * 2 + n_] = __builtin_amdgcn_mfma_f32_16x16x32_bf16(                 \
        a[m_][k_], b[n_][k_], acc[m_][(P) * 2 + n_], 0, 0, 0);                       \
  __builtin_amdgcn_s_setprio(0);

#define BAR_ONLY                                                                     \
  __builtin_amdgcn_sched_barrier(0);                                                 \
  __builtin_amdgcn_s_barrier();                                                      \
  __builtin_amdgcn_sched_barrier(0);

#define BAR_VM0                                                                      \
  __builtin_amdgcn_sched_barrier(0);                                                 \
  asm volatile("s_waitcnt vmcnt(0)" ::: "memory");                                   \
  __builtin_amdgcn_s_barrier();                                                      \
  __builtin_amdgcn_sched_barrier(0);

  // ---- x phase: stage (Abuf0 overlay), drain, MFMA (K=32) ----
  stageXA(0); stageXA(1); stageXB();
  BAR_VM0
  {
    short8 xb4[4];
#pragma unroll
    for (int nf = 0; nf < 4; ++nf)
      xb4[nf] = ldsr(16384 + (wn * 64 + nf * 16 + lc) * 64 + ((lk * 16) ^ swzx));
    __builtin_amdgcn_s_setprio(1);
#pragma unroll
    for (int mf = 0; mf < 4; ++mf) {
      short8 xa = ldsr((wm * 64 + mf * 16 + lc) * 64 + ((lk * 16) ^ swzx));
#pragma unroll
      for (int nf = 0; nf < 4; ++nf)
        acc[mf][nf] = __builtin_amdgcn_mfma_f32_16x16x32_bf16(xa, xb4[nf], acc[mf][nf], 0, 0, 0);
    }
    __builtin_amdgcn_s_setprio(0);
  }

  if (!first) {
    BAR_ONLY                                   // x reads consumed; Abuf0/Bbuf overlays free
    // ---- tile 0 stage: A(0) -> Abuf0, B(0) -> Bbuf ----
#pragma unroll
    for (int j = 0; j < 4; ++j) stageA(0, 0, j);
    stageB(0, 0); stageB(0, 1);
    BAR_VM0
    // ---- main loop: A-dbuf top-staging, small exposed B phase ----
    for (int kt = 0; kt < NT_; ++kt) {
      const int curA = (kt & 1) * 32768;       // byte base of A(kt)
      if (kt + 1 < NT_) {
        const int nxtAu = ((kt + 1) & 1) * 16384;  // ushort base of A(kt+1)
#pragma unroll
        for (int j = 0; j < 4; ++j) stageA(nxtAu, kt + 1, j);  // overlaps compute
      }
      LOAD_A(curA)
      LOAD_B(0)
      MFMA_P(0)
      LOAD_B(1)
      MFMA_P(1)
      if (kt + 1 < NT_) {
        BAR_ONLY                               // B(kt) reads retired (WAR for Bbuf)
        stageB(kt + 1, 0); stageB(kt + 1, 1);
        BAR_VM0                                // B(kt+1) landed; A(kt+1) landed (issued early)
      }
    }
  }

  // ---- epilogue: frag nf == gate; fused LSTM cell update; c in fp16 ----
  const int jj  = (by * 2 + wn) * 16 + lc;     // h column 0..1023
  const float bi  = bias[jj];
  const float bf_ = bias[H_ + jj];
  const float bg_ = bias[2 * H_ + jj];
  const float bo_ = bias[3 * H_ + jj];
#pragma unroll
  for (int mf = 0; mf < 4; ++mf) {
    const int rbase = m0 + wm * 64 + mf * 16 + lk * 4;
#pragma unroll
    for (int r = 0; r < 4; ++r) {
      const size_t idx = (size_t)(rbase + r) * H_ + jj;
      float ig = sigm(acc[mf][0][r] + bi);
      float fg = sigm(acc[mf][1][r] + bf_);
      float gg = tanh_f(acc[mf][2][r] + bg_);
      float og = sigm(acc[mf][3][r] + bo_);
      float cp = first ? 0.f : __half2float(__ushort_as_half(cst[idx]));
      float cn = fg * cp + ig * gg;
      cst[idx] = __half_as_ushort(__float2half(cn));
      hnext[idx] = f2bf(og * tanh_f(cn));
    }
  }
#undef LOAD_A
#undef LOAD_B
#undef MFMA_P
#undef BAR_ONLY
#undef BAR_VM0
}

// ---------- classifier: out = h @ Wc + bc ----------
__global__ __launch_bounds__(256) void cls_kernel(const unsigned short* __restrict__ h,
                                                  const float* __restrict__ wc,
                                                  const float* __restrict__ bc,
                                                  float* __restrict__ out) {
  int w = threadIdx.x >> 6, l = threadIdx.x & 63;
  int row = blockIdx.x * 4 + w;
  float acc[OUT_];
#pragma unroll
  for (int o = 0; o < OUT_; ++o) acc[o] = 0.f;
  const unsigned short* hr = h + row * H_;
  for (int k = l; k < H_; k += 64) {
    float hv = bf2f(hr[k]);
#pragma unroll
    for (int o = 0; o < OUT_; ++o) acc[o] += hv * wc[k * OUT_ + o];
  }
#pragma unroll
  for (int o = 0; o < OUT_; ++o) {
    float v = acc[o];
#pragma unroll
    for (int s = 32; s > 0; s >>= 1) v += __shfl_down(v, s, 64);
    if (l == 0) out[row * OUT_ + o] = v + bc[o];
  }
}

extern "C" void kernel_launch(void* const* d_in, const int* in_sizes, int n_in,
                              void* d_out, int out_size, void* d_ws, size_t ws_size,
                              hipStream_t stream) {
  const float* x    = (const float*)d_in[0];
  const float* wih  = (const float*)d_in[1];
  const float* whh  = (const float*)d_in[2];
  const float* bias = (const float*)d_in[3];
  const float* wc   = (const float*)d_in[4];
  const float* bc   = (const float*)d_in[5];
  float* out = (float*)d_out;

  char* ws = (char*)d_ws;
  unsigned short* wp  = (unsigned short*)(ws);                 //  8 MB  permuted W_hh^T bf16
  unsigned short* wip = (unsigned short*)(ws + 8388608);       //  256KB permuted W_ih^T bf16
  unsigned short* xb  = (unsigned short*)(ws + 8650752);       //  7 MB  x bf16 [T][B][32]
  unsigned short* h0  = (unsigned short*)(ws + 15990784);      //  8 MB
  unsigned short* h1  = (unsigned short*)(ws + 24379392);      //  8 MB
  unsigned short* cst = (unsigned short*)(ws + 32768000);      //  8 MB  fp16 cell state

  hipLaunchKernelGGL(conv_x_kernel,  dim3(448), dim3(256), 0, stream, x, xb);
  hipLaunchKernelGGL(perm_whh_kernel, dim3(256), dim3(256), 0, stream, whh, wp);
  hipLaunchKernelGGL(perm_wih_kernel, dim3(256), dim3(256), 0, stream, wih, wip);

  unsigned short* hb[2] = {h0, h1};
  for (int t = 0; t < T_; ++t) {
    unsigned short* hn = hb[t & 1];
    unsigned short* hp = hb[(t & 1) ^ 1];
    hipLaunchKernelGGL(lstm_step_kernel, dim3(512), dim3(512), 0, stream,
                       hp, wp, xb + (size_t)t * (B_ * 32), wip, bias, cst, hn,
                       (t == 0) ? 1 : 0);
  }
  hipLaunchKernelGGL(cls_kernel, dim3(1024), dim3(256), 0, stream, hb[1], wc, bc, out);
}